// Round 6
// baseline (480.824 us; speedup 1.0000x reference)
//
#include <hip/hip_runtime.h>
#include <math.h>

#define N_NODES 20000
#define N_EDGES 320000
#define N_GRAPHS 64
#define D_IN 1280
#define D_H 512
#define D_FC 1024
#define OUT_DIMS 5000
#define BKT_CAP 64  // max degree capacity (true max ~38 for Poisson(16) over 20k nodes)
#define PSPLIT 8    // pool node-split factor

typedef unsigned short ushort_t;
typedef short bf16x8 __attribute__((ext_vector_type(8)));
typedef float f32x4 __attribute__((ext_vector_type(4)));

__device__ __forceinline__ ushort_t f2b(float x) {
    unsigned u = __float_as_uint(x);
    unsigned r = (u + 0x7FFFu + ((u >> 16) & 1u)) >> 16;  // RNE
    return (ushort_t)r;
}

// packed f32x2 -> bf16x2, RNE (bit-identical to f2b for normal values)
__device__ __forceinline__ unsigned cvt_pk(float lo, float hi) {
    unsigned r;
    asm("v_cvt_pk_bf16_f32 %0, %1, %2" : "=v"(r) : "v"(lo), "v"(hi));
    return r;
}

// raw barrier + counted waits: prefetch DMAs stay in flight across barriers
#define BAR() asm volatile("s_barrier" ::: "memory")
#define WAITVM(n) asm volatile("s_waitcnt vmcnt(" #n ")" ::: "memory")
#define WAITLG() asm volatile("s_waitcnt lgkmcnt(0)" ::: "memory")
#define SCHED0() __builtin_amdgcn_sched_barrier(0)

// async 16B global->LDS DMA: per-lane gptr, wave-uniform LDS base + lane*16
#define GLL16(gp, lp)                                                                  \
    __builtin_amdgcn_global_load_lds((const __attribute__((address_space(1))) void*)(gp), \
                                     (__attribute__((address_space(3))) void*)(lp), 16, 0, 0)

// XCD swizzle for conv GEMMs: grid (32, 20) -> f in [0,640)
// 4 col-tiles of a row-tile share f&7 (same XCD) -> A row-panel L2-resident
#define CONV_SWIZZLE()                                         \
    const int f = blockIdx.y * 32 + blockIdx.x;                \
    const int rt = (f >> 5) * 8 + (f & 7);                     \
    const int ct = (f & 31) >> 3;                              \
    const int rowBase = rt * 128;                              \
    const int colBase = ct * 128;                              \
    if (rowBase >= M) return;

// ===================== BK=64 layout =====================
// Tile row = 64 bf16 = 8 chunks of 16B (128 B). Linear would be 16-way bank
// conflict on ds_read_b128 (stride 128B); chunk position in LDS = q ^ (row&7)
// (involution). DMA keeps LDS linear; the SOURCE global chunk is pre-swizzled.
// Slot s (16B units, 1024/tile): row = s>>3, pos = s&7, global chunk = pos^(row&7).
// With slot strides of 256, q = (t&7)^((t>>3)&7) is invariant across a thread's
// 4 slots (rows differ by 32 == 0 mod 8).

// ============ bf16 MFMA GEMM, BK=64, counted-vmcnt DMA dbuf (conv2) ============
// ISSUE_TILE = 8 DMA ops/thread. Depth 2: top-of-iter WAITVM(8) lands tile k,
// keeps tile k+1 flying; last iter WAITVM(0).
__global__ __launch_bounds__(256) void mfma_gemm_db(const ushort_t* __restrict__ A,
                                                    const ushort_t* __restrict__ BT,
                                                    ushort_t* __restrict__ C,
                                                    int M, int N, int K) {
    __shared__ ushort_t lds[32768];  // A: [0,16384) bufs 0/1 ; B: [16384,32768)
    const int t = threadIdx.x;
    const int lane = t & 63, wave = t >> 6;
    const int wrow = (wave >> 1) * 64, wcol = (wave & 1) * 64;
    const int lo = lane & 15, quad = lane >> 4;
    CONV_SWIZZLE();

    // DMA sources: 4 slots/thread per operand, q invariant
    const int q = (t & 7) ^ ((t >> 3) & 7);
    const int rbase = t >> 3;  // +32*i
    const ushort_t* pa[4];
#pragma unroll
    for (int i = 0; i < 4; ++i) {
        int ar = rowBase + rbase + 32 * i;
        if (ar >= M) ar = M - 1;  // clamped rows never stored
        pa[i] = A + (size_t)ar * K + q * 8;
    }
    const ushort_t* pb = BT + (size_t)(colBase + rbase) * K + q * 8;
    const size_t bstep = (size_t)32 * K;

#define ISSUE_TILE(p)                                                         \
    {                                                                         \
        GLL16(pa[0], lds + (p) * 8192 + 0 * 2048 + wave * 512);               \
        GLL16(pa[1], lds + (p) * 8192 + 1 * 2048 + wave * 512);               \
        GLL16(pa[2], lds + (p) * 8192 + 2 * 2048 + wave * 512);               \
        GLL16(pa[3], lds + (p) * 8192 + 3 * 2048 + wave * 512);               \
        GLL16(pb + 0 * bstep, lds + 16384 + (p) * 8192 + 0 * 2048 + wave * 512); \
        GLL16(pb + 1 * bstep, lds + 16384 + (p) * 8192 + 1 * 2048 + wave * 512); \
        GLL16(pb + 2 * bstep, lds + 16384 + (p) * 8192 + 2 * 2048 + wave * 512); \
        GLL16(pb + 3 * bstep, lds + 16384 + (p) * 8192 + 3 * 2048 + wave * 512); \
        pa[0] += 64; pa[1] += 64; pa[2] += 64; pa[3] += 64; pb += 64;         \
    }

    // frag offsets (ushort units): row*64 + ((kk*4+quad)^(row&7))*8 ; row&7 = lo&7
    int offA[4][2], offB[4][2];
#pragma unroll
    for (int i = 0; i < 4; ++i)
#pragma unroll
        for (int kk = 0; kk < 2; ++kk) {
            offA[i][kk] = (wrow + i * 16 + lo) * 64 + (((kk << 2) | quad) ^ (lo & 7)) * 8;
            offB[i][kk] = (wcol + i * 16 + lo) * 64 + (((kk << 2) | quad) ^ (lo & 7)) * 8;
        }

    f32x4 acc[4][4] = {};
    const int NK = K >> 6;  // conv2: 8

    ISSUE_TILE(0);
    if (NK > 1) ISSUE_TILE(1);

    for (int k = 0; k < NK; ++k) {
        if (k + 1 < NK) { WAITVM(8); } else { WAITVM(0); }
        BAR();  // tile k landed for all waves
        const ushort_t* Ab = lds + (k & 1) * 8192;
        const ushort_t* Bb = lds + 16384 + (k & 1) * 8192;
        bf16x8 af[4][2], bfr[4][2];
#pragma unroll
        for (int i = 0; i < 4; ++i)
#pragma unroll
            for (int kk = 0; kk < 2; ++kk) {
                af[i][kk] = *(const bf16x8*)&Ab[offA[i][kk]];
                bfr[i][kk] = *(const bf16x8*)&Bb[offB[i][kk]];
            }
        WAITLG();  // frag reads complete
        BAR();     // buf (k&1) reusable
        if (k + 2 < NK) { ISSUE_TILE(k & 1); }
        SCHED0();
        __builtin_amdgcn_s_setprio(1);
#pragma unroll
        for (int kk = 0; kk < 2; ++kk)  // K-order: kk=0 then 1 (matches BK=32 pair)
#pragma unroll
            for (int i = 0; i < 4; ++i)
#pragma unroll
                for (int j = 0; j < 4; ++j)
                    acc[i][j] = __builtin_amdgcn_mfma_f32_16x16x32_bf16(af[i][kk], bfr[j][kk], acc[i][j], 0, 0, 0);
        __builtin_amdgcn_s_setprio(0);
    }
#undef ISSUE_TILE

#pragma unroll
    for (int i = 0; i < 4; ++i) {
        int row0 = rowBase + wrow + i * 16 + quad * 4;
#pragma unroll
        for (int j = 0; j < 4; ++j) {
            int col = colBase + wcol + j * 16 + lo;
            if (col >= N) continue;
#pragma unroll
            for (int r = 0; r < 4; ++r) {
                int row = row0 + r;
                if (row < M) C[(size_t)row * N + col] = f2b(acc[i][j][r]);
            }
        }
    }
}

// ============ f32-A bf16 MFMA GEMM (conv1), BK=64 ============
// A read as f32, cvt_pk in regs, ds_write into swizzled layout. B via DMA dbuf.
// Thread t stages row rA=t>>1, half hA=t&1: 32 f32 (8 float4) -> 4 chunk writes
// at pos (4hA+j)^(rA&7). vmcnt ledger: ISSUE_B=4, LOADA=8.
// Steady top-of-iter: outstanding = B(k+1):4 + A(k+1):8 = 12 (B(k) already
// retired by iter k-1's WRITEA dep-wait) -> WAITVM(12); last iter WAITVM(0).
__global__ __launch_bounds__(256) void mfma_gemm_af32(const float* __restrict__ A,
                                                      const ushort_t* __restrict__ BT,
                                                      ushort_t* __restrict__ C,
                                                      int M, int N, int K) {
    __shared__ ushort_t lds[32768];  // A: [0,16384) ; B: [16384,32768)
    const int t = threadIdx.x;
    const int lane = t & 63, wave = t >> 6;
    const int wrow = (wave >> 1) * 64, wcol = (wave & 1) * 64;
    const int lo = lane & 15, quad = lane >> 4;
    CONV_SWIZZLE();

    // B DMA (same mapping as db)
    const int q = (t & 7) ^ ((t >> 3) & 7);
    const int rbase = t >> 3;
    const ushort_t* pb = BT + (size_t)(colBase + rbase) * K + q * 8;
    const size_t bstep = (size_t)32 * K;
    ushort_t* ldsB = lds + 16384;

#define ISSUE_B(p)                                                        \
    {                                                                     \
        GLL16(pb + 0 * bstep, ldsB + (p) * 8192 + 0 * 2048 + wave * 512); \
        GLL16(pb + 1 * bstep, ldsB + (p) * 8192 + 1 * 2048 + wave * 512); \
        GLL16(pb + 2 * bstep, ldsB + (p) * 8192 + 2 * 2048 + wave * 512); \
        GLL16(pb + 3 * bstep, ldsB + (p) * 8192 + 3 * 2048 + wave * 512); \
        pb += 64;                                                         \
    }

    // A staging
    const int rA = t >> 1, hA = t & 1;
    int ar = rowBase + rA; if (ar >= M) ar = M - 1;  // clamped rows never stored
    const float* pA = A + (size_t)ar * K + hA * 32;
    const int swA = rA & 7;
    int wrA[4];
#pragma unroll
    for (int j = 0; j < 4; ++j) wrA[j] = rA * 64 + ((4 * hA + j) ^ swA) * 8;

    float4 va0, va1, va2, va3, va4, va5, va6, va7;
#define LOADA()                                  \
    {                                            \
        va0 = *(const float4*)(pA + 0);          \
        va1 = *(const float4*)(pA + 4);          \
        va2 = *(const float4*)(pA + 8);          \
        va3 = *(const float4*)(pA + 12);         \
        va4 = *(const float4*)(pA + 16);         \
        va5 = *(const float4*)(pA + 20);         \
        va6 = *(const float4*)(pA + 24);         \
        va7 = *(const float4*)(pA + 28);         \
        pA += 64;                                \
    }
#define WRITEA(p)                                                     \
    {                                                                 \
        uint4 u;                                                      \
        u.x = cvt_pk(va0.x, va0.y); u.y = cvt_pk(va0.z, va0.w);       \
        u.z = cvt_pk(va1.x, va1.y); u.w = cvt_pk(va1.z, va1.w);       \
        *(uint4*)&lds[(p) * 8192 + wrA[0]] = u;                       \
        u.x = cvt_pk(va2.x, va2.y); u.y = cvt_pk(va2.z, va2.w);       \
        u.z = cvt_pk(va3.x, va3.y); u.w = cvt_pk(va3.z, va3.w);       \
        *(uint4*)&lds[(p) * 8192 + wrA[1]] = u;                       \
        u.x = cvt_pk(va4.x, va4.y); u.y = cvt_pk(va4.z, va4.w);       \
        u.z = cvt_pk(va5.x, va5.y); u.w = cvt_pk(va5.z, va5.w);       \
        *(uint4*)&lds[(p) * 8192 + wrA[2]] = u;                       \
        u.x = cvt_pk(va6.x, va6.y); u.y = cvt_pk(va6.z, va6.w);       \
        u.z = cvt_pk(va7.x, va7.y); u.w = cvt_pk(va7.z, va7.w);       \
        *(uint4*)&lds[(p) * 8192 + wrA[3]] = u;                       \
    }

    int offA[4][2], offB[4][2];
#pragma unroll
    for (int i = 0; i < 4; ++i)
#pragma unroll
        for (int kk = 0; kk < 2; ++kk) {
            offA[i][kk] = (wrow + i * 16 + lo) * 64 + (((kk << 2) | quad) ^ (lo & 7)) * 8;
            offB[i][kk] = (wcol + i * 16 + lo) * 64 + (((kk << 2) | quad) ^ (lo & 7)) * 8;
        }

    f32x4 acc[4][4] = {};
    const int NK = K >> 6;  // 20 for D_IN

    // prologue: A0:8, B0:4, B1:4, WRITEA(0) [dep-waits A0], A1:8, drain ds
    LOADA();
    SCHED0();
    ISSUE_B(0);
    ISSUE_B(1);
    SCHED0();
    WRITEA(0);
    SCHED0();
    LOADA();
    SCHED0();
    WAITLG();

    for (int k = 0; k < NK; ++k) {
        if (k + 1 < NK) { WAITVM(12); } else { WAITVM(0); }  // B(k) landed
        BAR();  // buf (k&1) fully populated (A writes barriered last iter)
        const ushort_t* Ab = lds + (k & 1) * 8192;
        const ushort_t* Bb = ldsB + (k & 1) * 8192;
        bf16x8 af[4][2], bfr[4][2];
#pragma unroll
        for (int i = 0; i < 4; ++i)
#pragma unroll
            for (int kk = 0; kk < 2; ++kk) {
                af[i][kk] = *(const bf16x8*)&Ab[offA[i][kk]];
                bfr[i][kk] = *(const bf16x8*)&Bb[offB[i][kk]];
            }
        WAITLG();  // frag reads complete
        BAR();     // buf (k&1) reusable
        if (k + 2 < NK) { ISSUE_B(k & 1); }  // B(k+2)
        SCHED0();
        if (k + 1 < NK) {
            WRITEA((k + 1) & 1);  // dep-waits A(k+1) (loaded last iter)
            SCHED0();
            if (k + 2 < NK) { LOADA(); }  // A(k+2)
            SCHED0();
        }
        __builtin_amdgcn_s_setprio(1);
#pragma unroll
        for (int kk = 0; kk < 2; ++kk)
#pragma unroll
            for (int i = 0; i < 4; ++i)
#pragma unroll
                for (int j = 0; j < 4; ++j)
                    acc[i][j] = __builtin_amdgcn_mfma_f32_16x16x32_bf16(af[i][kk], bfr[j][kk], acc[i][j], 0, 0, 0);
        __builtin_amdgcn_s_setprio(0);
        WAITLG();  // A ds_writes drained before next top barrier
    }
#undef ISSUE_B
#undef LOADA
#undef WRITEA

#pragma unroll
    for (int i = 0; i < 4; ++i) {
        int row0 = rowBase + wrow + i * 16 + quad * 4;
#pragma unroll
        for (int j = 0; j < 4; ++j) {
            int col = colBase + wcol + j * 16 + lo;
            if (col >= N) continue;
#pragma unroll
            for (int r = 0; r < 4; ++r) {
                int row = row0 + r;
                if (row < M) C[(size_t)row * N + col] = f2b(acc[i][j][r]);
            }
        }
    }
}

// ================= fused prep kernel =================
#define PREP_ZB 5
#define PREP_T1 640
#define PREP_T2 256
#define PREP_NBLK (PREP_ZB + PREP_T1 + PREP_T2 + 1)

__global__ __launch_bounds__(256) void prep_all(const float* __restrict__ W1src, ushort_t* __restrict__ w1t,
                                                const float* __restrict__ W2src, ushort_t* __restrict__ w2t,
                                                int* __restrict__ zbase,  // cursor
                                                const int* __restrict__ batch, int* __restrict__ gstart) {
    __shared__ float tile[32][33];
    int b = blockIdx.x;
    const int t = threadIdx.x;

    if (b < PREP_ZB) {  // zero 20000 ints
        int i = b * 256 + t;
        if (i < 1250) {
            int4* p = (int4*)zbase + (size_t)i * 4;
            int4 z = {0, 0, 0, 0};
            p[0] = z; p[1] = z; p[2] = z; p[3] = z;
        }
        return;
    }
    b -= PREP_ZB;

    if (b < PREP_T1 + PREP_T2) {  // tiled transpose + cvt
        const float* W;
        ushort_t* WT;
        int K, N, tb;
        if (b < PREP_T1) { W = W1src; WT = w1t; K = D_IN; N = D_H; tb = b; }
        else             { W = W2src; WT = w2t; K = D_H;  N = D_H; tb = b - PREP_T1; }
        const int ntn = N >> 5;
        const int kt = tb / ntn, nt = tb - kt * ntn;
        const int tx = t & 31, ty = t >> 5;
#pragma unroll
        for (int it = 0; it < 4; ++it) {
            int k = kt * 32 + ty + it * 8;
            tile[ty + it * 8][tx] = W[(size_t)k * N + nt * 32 + tx];
        }
        __syncthreads();
#pragma unroll
        for (int it = 0; it < 4; ++it) {
            int n = nt * 32 + ty + it * 8;
            WT[(size_t)n * K + kt * 32 + tx] = f2b(tile[tx][ty + it * 8]);
        }
        return;
    }

    // graph_bounds
    if (t <= N_GRAPHS) {
        int lo = 0, hi = N_NODES;
        while (lo < hi) {
            int mid = (lo + hi) >> 1;
            if (batch[mid] < t) lo = mid + 1; else hi = mid;
        }
        gstart[t] = lo;
    }
}

// ---------------- bucket CSR (no scan): col[d*64+p] ----------------
__global__ void fill_bucket(const int* __restrict__ src, const int* __restrict__ dst,
                            int* __restrict__ cursor, int* __restrict__ col) {
    int e = blockIdx.x * blockDim.x + threadIdx.x;
    if (e < N_EDGES) {
        int d = dst[e];
        int p = atomicAdd(cursor + d, 1);
        if (p < BKT_CAP) col[(d << 6) + p] = src[e];
    }
}

// dinv = rsqrt(true_degree + 1); cursor holds true degree after fill_bucket
__global__ void compute_dinv(const int* __restrict__ deg, float* __restrict__ dinv) {
    int v = blockIdx.x * blockDim.x + threadIdx.x;
    if (v < N_NODES) dinv[v] = rsqrtf((float)deg[v] + 1.0f);
}

// ---------------- fp32 split-K tiled GEMM (FC head) ----------------
__global__ __launch_bounds__(256) void gemm_splitk(const float* __restrict__ A,
                                                   const float* __restrict__ B,
                                                   float* __restrict__ P,
                                                   int M, int N, int K, int KC) {
    __shared__ float As[16][64];
    __shared__ float Bs[16][64];
    const int t = threadIdx.x;
    const int tx = t & 15, ty = t >> 4;
    const int rowBase = blockIdx.y * 64;
    const int colBase = blockIdx.x * 64;
    const int kbeg = blockIdx.z * KC;
    const int kend = kbeg + KC;
    float acc[4][4] = {};
    for (int k0 = kbeg; k0 < kend; k0 += 16) {
#pragma unroll
        for (int i = 0; i < 4; ++i) {
            int idx = t + i * 256;
            int row = idx >> 4, kk = idx & 15;
            int gr = rowBase + row;
            As[kk][row] = (gr < M) ? A[(size_t)gr * K + k0 + kk] : 0.f;
        }
#pragma unroll
        for (int i = 0; i < 4; ++i) {
            int idx = t + i * 256;
            int kk = idx >> 6, col = idx & 63;
            int gc = colBase + col;
            Bs[kk][col] = (gc < N) ? B[(size_t)(k0 + kk) * N + gc] : 0.f;
        }
        __syncthreads();
#pragma unroll
        for (int kk = 0; kk < 16; ++kk) {
            float a[4], bb[4];
#pragma unroll
            for (int i = 0; i < 4; ++i) a[i] = As[kk][ty * 4 + i];
#pragma unroll
            for (int j = 0; j < 4; ++j) bb[j] = Bs[kk][tx * 4 + j];
#pragma unroll
            for (int i = 0; i < 4; ++i)
#pragma unroll
                for (int j = 0; j < 4; ++j) acc[i][j] = fmaf(a[i], bb[j], acc[i][j]);
        }
        __syncthreads();
    }
    float* Pz = P + (size_t)blockIdx.z * M * N;
#pragma unroll
    for (int i = 0; i < 4; ++i) {
        int gr = rowBase + ty * 4 + i;
        if (gr >= M) continue;
#pragma unroll
        for (int j = 0; j < 4; ++j) {
            int gc = colBase + tx * 4 + j;
            if (gc < N) Pz[(size_t)gr * N + gc] = acc[i][j];
        }
    }
}

__global__ void reduce_bias_relu(const float* __restrict__ P, const float* __restrict__ b,
                                 float* __restrict__ out, int total, int N, int S) {
    int i = blockIdx.x * blockDim.x + threadIdx.x;
    if (i >= total) return;
    float s = 0.f;
    for (int z = 0; z < S; ++z) s += P[(size_t)z * total + i];
    out[i] = fmaxf(s + b[i % N], 0.f);
}

__global__ void reduce_bn_sigmoid(const float* __restrict__ P, const float* __restrict__ b2,
                                  const float* __restrict__ gamma, const float* __restrict__ beta,
                                  float* __restrict__ out, int S) {
    int i = blockIdx.x * blockDim.x + threadIdx.x;
    if (i >= N_GRAPHS * OUT_DIMS) return;
    int c = i % OUT_DIMS;
    float s = 0.f;
    for (int z = 0; z < S; ++z) s += P[(size_t)z * N_GRAPHS * OUT_DIMS + i];
    const float sc = 0.9999950000374997f;  // 1/sqrt(1+1e-5)
    float zz = (s + b2[c]) * (gamma[c] * sc) + beta[c];
    out[i] = 1.f / (1.f + expf(-zz));
}

// ---------------- bf16 gather-aggregate ----------------
__device__ __forceinline__ void bf8_fma(uint4 v, float c, float* acc) {
    unsigned a[4] = {v.x, v.y, v.z, v.w};
#pragma unroll
    for (int i = 0; i < 4; ++i) {
        float lo = __uint_as_float(a[i] << 16);
        float hi = __uint_as_float(a[i] & 0xFFFF0000u);
        acc[2 * i]     = fmaf(lo, c, acc[2 * i]);
        acc[2 * i + 1] = fmaf(hi, c, acc[2 * i + 1]);
    }
}

__device__ __forceinline__ void agg_node_bf16(const ushort_t* __restrict__ H,
                                              const int* __restrict__ deg,
                                              const int* __restrict__ col,
                                              const float* __restrict__ dinv,
                                              const float* __restrict__ bias,
                                              int v, int f, float* r) {
    const int beg = v << 6;
    int d = deg[v]; if (d > BKT_CAP) d = BKT_CAP;
    const int end = beg + d;
    const float dv = dinv[v];
    float acc[8] = {};
    int j = beg;
    for (; j + 7 < end; j += 8) {
        int s[8];
#pragma unroll
        for (int u = 0; u < 8; ++u) s[u] = col[j + u];
        float c[8];
#pragma unroll
        for (int u = 0; u < 8; ++u) c[u] = dinv[s[u]] * dv;
        uint4 h[8];
#pragma unroll
        for (int u = 0; u < 8; ++u) h[u] = *(const uint4*)(H + (size_t)s[u] * D_H + f);
#pragma unroll
        for (int u = 0; u < 8; ++u) bf8_fma(h[u], c[u], acc);
    }
    for (; j + 3 < end; j += 4) {
        int s0 = col[j], s1 = col[j + 1], s2 = col[j + 2], s3 = col[j + 3];
        float c0 = dinv[s0] * dv, c1 = dinv[s1] * dv;
        float c2 = dinv[s2] * dv, c3 = dinv[s3] * dv;
        uint4 h0 = *(const uint4*)(H + (size_t)s0 * D_H + f);
        uint4 h1 = *(const uint4*)(H + (size_t)s1 * D_H + f);
        uint4 h2 = *(const uint4*)(H + (size_t)s2 * D_H + f);
        uint4 h3 = *(const uint4*)(H + (size_t)s3 * D_H + f);
        bf8_fma(h0, c0, acc);
        bf8_fma(h1, c1, acc);
        bf8_fma(h2, c2, acc);
        bf8_fma(h3, c3, acc);
    }
    for (; j < end; ++j) {
        int s0 = col[j];
        float c0 = dinv[s0] * dv;
        uint4 h0 = *(const uint4*)(H + (size_t)s0 * D_H + f);
        bf8_fma(h0, c0, acc);
    }
    uint4 hv = *(const uint4*)(H + (size_t)v * D_H + f);
    bf8_fma(hv, dv * dv, acc);  // self-loop
    float4 b0 = *(const float4*)(bias + f);
    float4 b1 = *(const float4*)(bias + f + 4);
    r[0] = fmaxf(acc[0] + b0.x, 0.f);
    r[1] = fmaxf(acc[1] + b0.y, 0.f);
    r[2] = fmaxf(acc[2] + b0.z, 0.f);
    r[3] = fmaxf(acc[3] + b0.w, 0.f);
    r[4] = fmaxf(acc[4] + b1.x, 0.f);
    r[5] = fmaxf(acc[5] + b1.y, 0.f);
    r[6] = fmaxf(acc[6] + b1.z, 0.f);
    r[7] = fmaxf(acc[7] + b1.w, 0.f);
}

// 4 nodes per block (one per wave)
__global__ __launch_bounds__(256) void gather_agg_relu_bf16(const ushort_t* __restrict__ H,
                                                            const int* __restrict__ deg,
                                                            const int* __restrict__ col,
                                                            const float* __restrict__ dinv,
                                                            const float* __restrict__ bias,
                                                            ushort_t* __restrict__ out) {
    const int v = blockIdx.x * 4 + (threadIdx.x >> 6);
    const int f = (threadIdx.x & 63) * 8;
    float r[8];
    agg_node_bf16(H, deg, col, dinv, bias, v, f, r);
    ushort_t o[8];
#pragma unroll
    for (int i = 0; i < 8; ++i) o[i] = f2b(r[i]);
    *(uint4*)(out + (size_t)v * D_H + f) = *(uint4*)o;
}

// ---------------- segment max pool: node-split partial + reduce ----------------
__global__ __launch_bounds__(256) void pool_max_partial(const ushort_t* __restrict__ h2,
                                                        const int* __restrict__ gstart,
                                                        float* __restrict__ pbuf) {
    const int g = blockIdx.x;
    const int s = blockIdx.y;
    const int f = threadIdx.x * 2;
    const int beg = gstart[g], end = gstart[g + 1];
    const int len = end - beg;
    const int chunk = (len + PSPLIT - 1) / PSPLIT;
    int lo = beg + s * chunk;
    int hi = lo + chunk; if (hi > end) hi = end;
    float m0 = -INFINITY, m1 = -INFINITY;
    int v = lo;
    for (; v + 3 < hi; v += 4) {
        unsigned u0 = *(const unsigned*)(h2 + (size_t)(v + 0) * D_H + f);
        unsigned u1 = *(const unsigned*)(h2 + (size_t)(v + 1) * D_H + f);
        unsigned u2 = *(const unsigned*)(h2 + (size_t)(v + 2) * D_H + f);
        unsigned u3 = *(const unsigned*)(h2 + (size_t)(v + 3) * D_H + f);
        m0 = fmaxf(m0, fmaxf(fmaxf(__uint_as_float(u0 << 16), __uint_as_float(u1 << 16)),
                             fmaxf(__uint_as_float(u2 << 16), __uint_as_float(u3 << 16))));
        m1 = fmaxf(m1, fmaxf(fmaxf(__uint_as_float(u0 & 0xFFFF0000u), __uint_as_float(u1 & 0xFFFF0000u)),
                             fmaxf(__uint_as_float(u2 & 0xFFFF0000u), __uint_as_float(u3 & 0xFFFF0000u))));
    }
    for (; v < hi; ++v) {
        unsigned u = *(const unsigned*)(h2 + (size_t)v * D_H + f);
        m0 = fmaxf(m0, __uint_as_float(u << 16));
        m1 = fmaxf(m1, __uint_as_float(u & 0xFFFF0000u));
    }
    float* p = pbuf + ((size_t)s * N_GRAPHS + g) * D_H + f;
    p[0] = m0;
    p[1] = m1;
}

__global__ void pool_max_final(const float* __restrict__ pbuf, float* __restrict__ gbuf) {
    int i = blockIdx.x * blockDim.x + threadIdx.x;
    if (i >= N_GRAPHS * D_H) return;
    float m = -INFINITY;
#pragma unroll
    for (int s = 0; s < PSPLIT; ++s) m = fmaxf(m, pbuf[(size_t)s * N_GRAPHS * D_H + i]);
    gbuf[i] = m;
}

extern "C" void kernel_launch(void* const* d_in, const int* in_sizes, int n_in,
                              void* d_out, int out_size, void* d_ws, size_t ws_size,
                              hipStream_t stream) {
    const float* x     = (const float*)d_in[0];
    const int*   ei    = (const int*)d_in[1];
    const int*   batch = (const int*)d_in[2];
    const float* Wg1   = (const float*)d_in[3];
    const float* bg1   = (const float*)d_in[4];
    const float* Wg2   = (const float*)d_in[5];
    const float* bg2   = (const float*)d_in[6];
    const float* W1    = (const float*)d_in[7];
    const float* b1    = (const float*)d_in[8];
    const float* W2    = (const float*)d_in[9];
    const float* b2    = (const float*)d_in[10];
    const float* gamma = (const float*)d_in[11];
    const float* beta  = (const float*)d_in[12];
    const int* src = ei;
    const int* dst = ei + N_EDGES;
    float* out = (float*)d_out;

    const int S1 = 8;  // fc1 K-split
    const int S2 = 8;  // fc2 K-split

    // workspace layout (16B-aligned)
    ushort_t* hpre   = (ushort_t*)d_ws;                        // [N_NODES, D_H] bf16
    ushort_t* h1b    = hpre + (size_t)N_NODES * D_H;           // [N_NODES, D_H] bf16
    ushort_t* w1t    = h1b + (size_t)N_NODES * D_H;            // [D_H, D_IN] bf16
    ushort_t* w2t    = w1t + (size_t)D_H * D_IN;               // [D_H, D_H] bf16
    float*    dinv   = (float*)(w2t + (size_t)D_H * D_H);      // [N_NODES]
    float*    gbuf   = dinv + N_NODES;                         // [N_GRAPHS, D_H]
    float*    pbuf   = gbuf + N_GRAPHS * D_H;                  // [PSPLIT, N_GRAPHS, D_H]
    float*    fc1o   = pbuf + (size_t)PSPLIT * N_GRAPHS * D_H; // [N_GRAPHS, D_FC]
    float*    part1  = fc1o + N_GRAPHS * D_FC;                 // [S1, 64, D_FC]
    float*    part2  = part1 + (size_t)S1 * N_GRAPHS * D_FC;   // [S2, 64, OUT_DIMS]
    int*      cursor = (int*)(part2 + (size_t)S2 * N_GRAPHS * OUT_DIMS);  // [N_NODES] -> degree
    int*      colbkt = cursor + N_NODES;                       // [N_NODES * BKT_CAP]
    int*      gstart = colbkt + (size_t)N_NODES * BKT_CAP;     // [N_GRAPHS+1]

    // ---- fused prep: zero cursor + W1^T + W2^T + graph bounds ----
    prep_all<<<PREP_NBLK, 256, 0, stream>>>(Wg1, w1t, Wg2, w2t, cursor, batch, gstart);

    // ---- bucket adjacency build ----
    fill_bucket<<<(N_EDGES + 255) / 256, 256, 0, stream>>>(src, dst, cursor, colbkt);
    compute_dinv<<<(N_NODES + 255) / 256, 256, 0, stream>>>(cursor, dinv);

    dim3 gconv(32, 20);  // 640 slots, 628 active (157 row-tiles x 4 col-tiles)

    // conv1: hpre = bf16(x @ Wg1), A consumed as f32 in-kernel ; gather+relu -> h1b
    mfma_gemm_af32<<<gconv, 256, 0, stream>>>(x, w1t, hpre, N_NODES, D_H, D_IN);
    gather_agg_relu_bf16<<<N_NODES / 4, 256, 0, stream>>>(hpre, cursor, colbkt, dinv, bg1, h1b);

    // conv2: hpre = bf16(h1b @ Wg2) ; gather+relu -> h2 (reuse h1b) ; pool
    mfma_gemm_db<<<gconv, 256, 0, stream>>>(h1b, w2t, hpre, N_NODES, D_H, D_H);
    gather_agg_relu_bf16<<<N_NODES / 4, 256, 0, stream>>>(hpre, cursor, colbkt, dinv, bg2, h1b);
    pool_max_partial<<<dim3(N_GRAPHS, PSPLIT), 256, 0, stream>>>(h1b, gstart, pbuf);
    pool_max_final<<<(N_GRAPHS * D_H + 255) / 256, 256, 0, stream>>>(pbuf, gbuf);

    // fc1: [64,512]@[512,1024] split-K=8 -> part1 ; reduce + b1 + relu -> fc1o
    dim3 gfc1((D_FC + 63) / 64, 1, S1);
    gemm_splitk<<<gfc1, 256, 0, stream>>>(gbuf, W1, part1, N_GRAPHS, D_FC, D_H, D_H / S1);
    reduce_bias_relu<<<(N_GRAPHS * D_FC + 255) / 256, 256, 0, stream>>>(
        part1, b1, fc1o, N_GRAPHS * D_FC, D_FC, S1);

    // fc2: [64,1024]@[1024,5000] split-K=8 -> part2 ; reduce + BN + sigmoid -> out
    dim3 gfc2((OUT_DIMS + 63) / 64, 1, S2);
    gemm_splitk<<<gfc2, 256, 0, stream>>>(fc1o, W2, part2, N_GRAPHS, OUT_DIMS, D_FC, D_FC / S2);
    reduce_bn_sigmoid<<<(N_GRAPHS * OUT_DIMS + 255) / 256, 256, 0, stream>>>(
        part2, b2, gamma, beta, out, S2);
}

// Round 7
// 444.134 us; speedup vs baseline: 1.0826x; 1.0826x over previous
//
#include <hip/hip_runtime.h>
#include <math.h>

#define N_NODES 20000
#define N_EDGES 320000
#define N_GRAPHS 64
#define D_IN 1280
#define D_H 512
#define D_FC 1024
#define OUT_DIMS 5000
#define BKT_CAP 64  // max degree capacity (true max ~38 for Poisson(16) over 20k nodes)
#define PSPLIT 8    // pool node-split factor

typedef unsigned short ushort_t;
typedef short bf16x8 __attribute__((ext_vector_type(8)));
typedef float f32x4 __attribute__((ext_vector_type(4)));

__device__ __forceinline__ ushort_t f2b(float x) {
    unsigned u = __float_as_uint(x);
    unsigned r = (u + 0x7FFFu + ((u >> 16) & 1u)) >> 16;  // RNE
    return (ushort_t)r;
}

#define WAITVM(n) asm volatile("s_waitcnt vmcnt(" #n ")" ::: "memory")
#define WAITLG() asm volatile("s_waitcnt lgkmcnt(0)" ::: "memory")
#define SCHED0() __builtin_amdgcn_sched_barrier(0)

// async 16B global->LDS DMA: per-lane gptr, wave-uniform LDS base (HW adds lane*16)
#define GLL16(gp, lp)                                                                  \
    __builtin_amdgcn_global_load_lds((const __attribute__((address_space(1))) void*)(gp), \
                                     (__attribute__((address_space(3))) void*)(lp), 16, 0, 0)

// ============ 1-wave 64x64 bf16 MFMA GEMM, BK=32, barrier-free ============
// Grid: 2504 = 313 row-tiles x 8 col-tiles, 64 threads/block (one wave).
// No s_barrier anywhere: the single wave orders LDS reuse with its own
// vmcnt/lgkmcnt ledger. DMA depth 2 (2 A-bufs + 2 B-bufs, 16 KB LDS).
// XCD swizzle: v = (bid&7)*313 + (bid>>3) -> each XCD gets a contiguous run
// of row-tiles; the 8 col-tiles of a row-panel stay on one XCD's L2.
// LDS layout (per 64x32 tile, 2048 ushorts): row r occupies 4 chunks of 16B;
// chunk q of row r lives at slot q^((r>>1)&3) (same swizzle as the verified
// 128-tile kernel). DMA slot s (lane+64i): row=(lane>>2)+16i, global chunk
// q=(lane&3)^((lane>>3)&3) (invariant across i). Frag read: row i*16+lo,
// chunk qs=(quad^((lo>>1)&3)).
__global__ __launch_bounds__(64) void mfma_gemm_1w(const ushort_t* __restrict__ A,
                                                   const ushort_t* __restrict__ BT,
                                                   ushort_t* __restrict__ C,
                                                   int M, int N, int K) {
    __shared__ ushort_t lds[8192];  // A bufs: 0,2048 ; B bufs: 4096,6144 (ushort units)
    const int lane = threadIdx.x;
    const int lo = lane & 15, quad = lane >> 4;

    const int bid = blockIdx.x;
    const int v = (bid & 7) * 313 + (bid >> 3);  // bijective: 2504 = 8*313
    const int rowBase = (v >> 3) * 64;
    const int colBase = (v & 7) * 64;

    // DMA sources: 4 slots per operand per tile
    const int q = (lane & 3) ^ ((lane >> 3) & 3);
    const int rb = lane >> 2;
    const ushort_t* pa[4];
    const ushort_t* pb[4];
#pragma unroll
    for (int i = 0; i < 4; ++i) {
        int ar = rowBase + rb + 16 * i;
        if (ar >= M) ar = M - 1;  // clamped rows never stored
        pa[i] = A + (size_t)ar * K + q * 8;
        pb[i] = BT + (size_t)(colBase + rb + 16 * i) * K + q * 8;  // N=512 exact, no clamp
    }

#define ISSUE_TILE(p)                                      \
    {                                                      \
        GLL16(pa[0], lds + (p) * 2048 + 0 * 512);          \
        GLL16(pa[1], lds + (p) * 2048 + 1 * 512);          \
        GLL16(pa[2], lds + (p) * 2048 + 2 * 512);          \
        GLL16(pa[3], lds + (p) * 2048 + 3 * 512);          \
        GLL16(pb[0], lds + 4096 + (p) * 2048 + 0 * 512);   \
        GLL16(pb[1], lds + 4096 + (p) * 2048 + 1 * 512);   \
        GLL16(pb[2], lds + 4096 + (p) * 2048 + 2 * 512);   \
        GLL16(pb[3], lds + 4096 + (p) * 2048 + 3 * 512);   \
        pa[0] += 32; pa[1] += 32; pa[2] += 32; pa[3] += 32; \
        pb[0] += 32; pb[1] += 32; pb[2] += 32; pb[3] += 32; \
    }

    const int qs = (quad ^ ((lo >> 1) & 3)) * 8;
    int offA[4], offB[4];
#pragma unroll
    for (int i = 0; i < 4; ++i) offA[i] = (i * 16 + lo) * 32 + qs;
#pragma unroll
    for (int j = 0; j < 4; ++j) offB[j] = (j * 16 + lo) * 32 + qs;

    f32x4 acc[4][4] = {};
    const int NK = K >> 5;

    ISSUE_TILE(0);
    ISSUE_TILE(1);

    for (int k = 0; k < NK; ++k) {
        if (k + 1 < NK) { WAITVM(8); } else { WAITVM(0); }  // tile k landed (private ledger)
        const ushort_t* Ab = lds + (k & 1) * 2048;
        const ushort_t* Bb = lds + 4096 + (k & 1) * 2048;
        bf16x8 af[4], bfr[4];
#pragma unroll
        for (int i = 0; i < 4; ++i) af[i] = *(const bf16x8*)&Ab[offA[i]];
#pragma unroll
        for (int j = 0; j < 4; ++j) bfr[j] = *(const bf16x8*)&Bb[offB[j]];
        WAITLG();  // frag reads retired -> buf (k&1) reusable
        if (k + 2 < NK) { ISSUE_TILE(k & 1); }  // refill flies under MFMA
        SCHED0();
#pragma unroll
        for (int i = 0; i < 4; ++i)
#pragma unroll
            for (int j = 0; j < 4; ++j)
                acc[i][j] = __builtin_amdgcn_mfma_f32_16x16x32_bf16(af[i], bfr[j], acc[i][j], 0, 0, 0);
    }
#undef ISSUE_TILE

#pragma unroll
    for (int i = 0; i < 4; ++i) {
        int row0 = rowBase + i * 16 + quad * 4;
#pragma unroll
        for (int j = 0; j < 4; ++j) {
            int col = colBase + j * 16 + lo;
            if (col >= N) continue;
#pragma unroll
            for (int r = 0; r < 4; ++r) {
                int row = row0 + r;
                if (row < M) C[(size_t)row * N + col] = f2b(acc[i][j][r]);
            }
        }
    }
}

// ================= fused prep kernel =================
// blocks [0,5):       zero cursor (20000 ints)
// blocks [5,645):     W1 (1280x512) transpose+cvt -> w1t (LDS 32x32 tiles)
// blocks [645,901):   W2 (512x512)  transpose+cvt -> w2t
// blocks [901,13401): x f32->bf16 (8 elems/thread)
// block  13401:       graph_bounds
#define PREP_ZB 5
#define PREP_T1 640
#define PREP_T2 256
#define PREP_XB 12500
#define PREP_NBLK (PREP_ZB + PREP_T1 + PREP_T2 + PREP_XB + 1)

__global__ __launch_bounds__(256) void prep_all(const float* __restrict__ W1src, ushort_t* __restrict__ w1t,
                                                const float* __restrict__ W2src, ushort_t* __restrict__ w2t,
                                                const float* __restrict__ x, ushort_t* __restrict__ xb,
                                                int* __restrict__ zbase,  // cursor
                                                const int* __restrict__ batch, int* __restrict__ gstart) {
    __shared__ float tile[32][33];
    int b = blockIdx.x;
    const int t = threadIdx.x;

    if (b < PREP_ZB) {  // zero 20000 ints
        int i = b * 256 + t;
        if (i < 1250) {
            int4* p = (int4*)zbase + (size_t)i * 4;
            int4 z = {0, 0, 0, 0};
            p[0] = z; p[1] = z; p[2] = z; p[3] = z;
        }
        return;
    }
    b -= PREP_ZB;

    if (b < PREP_T1 + PREP_T2) {  // tiled transpose + cvt
        const float* W;
        ushort_t* WT;
        int K, N, tb;
        if (b < PREP_T1) { W = W1src; WT = w1t; K = D_IN; N = D_H; tb = b; }
        else             { W = W2src; WT = w2t; K = D_H;  N = D_H; tb = b - PREP_T1; }
        const int ntn = N >> 5;
        const int kt = tb / ntn, nt = tb - kt * ntn;
        const int tx = t & 31, ty = t >> 5;
#pragma unroll
        for (int it = 0; it < 4; ++it) {
            int k = kt * 32 + ty + it * 8;
            tile[ty + it * 8][tx] = W[(size_t)k * N + nt * 32 + tx];
        }
        __syncthreads();
#pragma unroll
        for (int it = 0; it < 4; ++it) {
            int n = nt * 32 + ty + it * 8;
            WT[(size_t)n * K + kt * 32 + tx] = f2b(tile[tx][ty + it * 8]);
        }
        return;
    }
    b -= PREP_T1 + PREP_T2;

    if (b < PREP_XB) {  // x convert, 8 f32 -> 8 bf16 per thread
        int i = b * 256 + t;
        const float4* p = (const float4*)(x + (size_t)i * 8);
        float4 v0 = p[0], v1 = p[1];
        ushort_t w[8] = {f2b(v0.x), f2b(v0.y), f2b(v0.z), f2b(v0.w),
                         f2b(v1.x), f2b(v1.y), f2b(v1.z), f2b(v1.w)};
        *(uint4*)(xb + (size_t)i * 8) = *(uint4*)w;
        return;
    }

    // graph_bounds
    if (t <= N_GRAPHS) {
        int lo = 0, hi = N_NODES;
        while (lo < hi) {
            int mid = (lo + hi) >> 1;
            if (batch[mid] < t) lo = mid + 1; else hi = mid;
        }
        gstart[t] = lo;
    }
}

// ---------------- bucket CSR (no scan): col[d*64+p] ----------------
__global__ void fill_bucket(const int* __restrict__ src, const int* __restrict__ dst,
                            int* __restrict__ cursor, int* __restrict__ col) {
    int e = blockIdx.x * blockDim.x + threadIdx.x;
    if (e < N_EDGES) {
        int d = dst[e];
        int p = atomicAdd(cursor + d, 1);
        if (p < BKT_CAP) col[(d << 6) + p] = src[e];
    }
}

// dinv = rsqrt(true_degree + 1); cursor holds true degree after fill_bucket
__global__ void compute_dinv(const int* __restrict__ deg, float* __restrict__ dinv) {
    int v = blockIdx.x * blockDim.x + threadIdx.x;
    if (v < N_NODES) dinv[v] = rsqrtf((float)deg[v] + 1.0f);
}

// ---------------- fp32 split-K tiled GEMM (FC head) ----------------
__global__ __launch_bounds__(256) void gemm_splitk(const float* __restrict__ A,
                                                   const float* __restrict__ B,
                                                   float* __restrict__ P,
                                                   int M, int N, int K, int KC) {
    __shared__ float As[16][64];
    __shared__ float Bs[16][64];
    const int t = threadIdx.x;
    const int tx = t & 15, ty = t >> 4;
    const int rowBase = blockIdx.y * 64;
    const int colBase = blockIdx.x * 64;
    const int kbeg = blockIdx.z * KC;
    const int kend = kbeg + KC;
    float acc[4][4] = {};
    for (int k0 = kbeg; k0 < kend; k0 += 16) {
#pragma unroll
        for (int i = 0; i < 4; ++i) {
            int idx = t + i * 256;
            int row = idx >> 4, kk = idx & 15;
            int gr = rowBase + row;
            As[kk][row] = (gr < M) ? A[(size_t)gr * K + k0 + kk] : 0.f;
        }
#pragma unroll
        for (int i = 0; i < 4; ++i) {
            int idx = t + i * 256;
            int kk = idx >> 6, col = idx & 63;
            int gc = colBase + col;
            Bs[kk][col] = (gc < N) ? B[(size_t)(k0 + kk) * N + gc] : 0.f;
        }
        __syncthreads();
#pragma unroll
        for (int kk = 0; kk < 16; ++kk) {
            float a[4], bb[4];
#pragma unroll
            for (int i = 0; i < 4; ++i) a[i] = As[kk][ty * 4 + i];
#pragma unroll
            for (int j = 0; j < 4; ++j) bb[j] = Bs[kk][tx * 4 + j];
#pragma unroll
            for (int i = 0; i < 4; ++i)
#pragma unroll
                for (int j = 0; j < 4; ++j) acc[i][j] = fmaf(a[i], bb[j], acc[i][j]);
        }
        __syncthreads();
    }
    float* Pz = P + (size_t)blockIdx.z * M * N;
#pragma unroll
    for (int i = 0; i < 4; ++i) {
        int gr = rowBase + ty * 4 + i;
        if (gr >= M) continue;
#pragma unroll
        for (int j = 0; j < 4; ++j) {
            int gc = colBase + tx * 4 + j;
            if (gc < N) Pz[(size_t)gr * N + gc] = acc[i][j];
        }
    }
}

__global__ void reduce_bias_relu(const float* __restrict__ P, const float* __restrict__ b,
                                 float* __restrict__ out, int total, int N, int S) {
    int i = blockIdx.x * blockDim.x + threadIdx.x;
    if (i >= total) return;
    float s = 0.f;
    for (int z = 0; z < S; ++z) s += P[(size_t)z * total + i];
    out[i] = fmaxf(s + b[i % N], 0.f);
}

__global__ void reduce_bn_sigmoid(const float* __restrict__ P, const float* __restrict__ b2,
                                  const float* __restrict__ gamma, const float* __restrict__ beta,
                                  float* __restrict__ out, int S) {
    int i = blockIdx.x * blockDim.x + threadIdx.x;
    if (i >= N_GRAPHS * OUT_DIMS) return;
    int c = i % OUT_DIMS;
    float s = 0.f;
    for (int z = 0; z < S; ++z) s += P[(size_t)z * N_GRAPHS * OUT_DIMS + i];
    const float sc = 0.9999950000374997f;  // 1/sqrt(1+1e-5)
    float zz = (s + b2[c]) * (gamma[c] * sc) + beta[c];
    out[i] = 1.f / (1.f + expf(-zz));
}

// ---------------- bf16 gather-aggregate ----------------
__device__ __forceinline__ void bf8_fma(uint4 v, float c, float* acc) {
    unsigned a[4] = {v.x, v.y, v.z, v.w};
#pragma unroll
    for (int i = 0; i < 4; ++i) {
        float lo = __uint_as_float(a[i] << 16);
        float hi = __uint_as_float(a[i] & 0xFFFF0000u);
        acc[2 * i]     = fmaf(lo, c, acc[2 * i]);
        acc[2 * i + 1] = fmaf(hi, c, acc[2 * i + 1]);
    }
}

__device__ __forceinline__ void agg_node_bf16(const ushort_t* __restrict__ H,
                                              const int* __restrict__ deg,
                                              const int* __restrict__ col,
                                              const float* __restrict__ dinv,
                                              const float* __restrict__ bias,
                                              int v, int f, float* r) {
    const int beg = v << 6;
    int d = deg[v]; if (d > BKT_CAP) d = BKT_CAP;
    const int end = beg + d;
    const float dv = dinv[v];
    float acc[8] = {};
    int j = beg;
    for (; j + 7 < end; j += 8) {
        int s[8];
#pragma unroll
        for (int u = 0; u < 8; ++u) s[u] = col[j + u];
        float c[8];
#pragma unroll
        for (int u = 0; u < 8; ++u) c[u] = dinv[s[u]] * dv;
        uint4 h[8];
#pragma unroll
        for (int u = 0; u < 8; ++u) h[u] = *(const uint4*)(H + (size_t)s[u] * D_H + f);
#pragma unroll
        for (int u = 0; u < 8; ++u) bf8_fma(h[u], c[u], acc);
    }
    for (; j + 3 < end; j += 4) {
        int s0 = col[j], s1 = col[j + 1], s2 = col[j + 2], s3 = col[j + 3];
        float c0 = dinv[s0] * dv, c1 = dinv[s1] * dv;
        float c2 = dinv[s2] * dv, c3 = dinv[s3] * dv;
        uint4 h0 = *(const uint4*)(H + (size_t)s0 * D_H + f);
        uint4 h1 = *(const uint4*)(H + (size_t)s1 * D_H + f);
        uint4 h2 = *(const uint4*)(H + (size_t)s2 * D_H + f);
        uint4 h3 = *(const uint4*)(H + (size_t)s3 * D_H + f);
        bf8_fma(h0, c0, acc);
        bf8_fma(h1, c1, acc);
        bf8_fma(h2, c2, acc);
        bf8_fma(h3, c3, acc);
    }
    for (; j < end; ++j) {
        int s0 = col[j];
        float c0 = dinv[s0] * dv;
        uint4 h0 = *(const uint4*)(H + (size_t)s0 * D_H + f);
        bf8_fma(h0, c0, acc);
    }
    uint4 hv = *(const uint4*)(H + (size_t)v * D_H + f);
    bf8_fma(hv, dv * dv, acc);  // self-loop
    float4 b0 = *(const float4*)(bias + f);
    float4 b1 = *(const float4*)(bias + f + 4);
    r[0] = fmaxf(acc[0] + b0.x, 0.f);
    r[1] = fmaxf(acc[1] + b0.y, 0.f);
    r[2] = fmaxf(acc[2] + b0.z, 0.f);
    r[3] = fmaxf(acc[3] + b0.w, 0.f);
    r[4] = fmaxf(acc[4] + b1.x, 0.f);
    r[5] = fmaxf(acc[5] + b1.y, 0.f);
    r[6] = fmaxf(acc[6] + b1.z, 0.f);
    r[7] = fmaxf(acc[7] + b1.w, 0.f);
}

// 4 nodes per block (one per wave)
__global__ __launch_bounds__(256) void gather_agg_relu_bf16(const ushort_t* __restrict__ H,
                                                            const int* __restrict__ deg,
                                                            const int* __restrict__ col,
                                                            const float* __restrict__ dinv,
                                                            const float* __restrict__ bias,
                                                            ushort_t* __restrict__ out) {
    const int v = blockIdx.x * 4 + (threadIdx.x >> 6);
    const int f = (threadIdx.x & 63) * 8;
    float r[8];
    agg_node_bf16(H, deg, col, dinv, bias, v, f, r);
    ushort_t o[8];
#pragma unroll
    for (int i = 0; i < 8; ++i) o[i] = f2b(r[i]);
    *(uint4*)(out + (size_t)v * D_H + f) = *(uint4*)o;
}

// ---------------- segment max pool: node-split partial + reduce ----------------
__global__ __launch_bounds__(256) void pool_max_partial(const ushort_t* __restrict__ h2,
                                                        const int* __restrict__ gstart,
                                                        float* __restrict__ pbuf) {
    const int g = blockIdx.x;
    const int s = blockIdx.y;
    const int f = threadIdx.x * 2;
    const int beg = gstart[g], end = gstart[g + 1];
    const int len = end - beg;
    const int chunk = (len + PSPLIT - 1) / PSPLIT;
    int lo = beg + s * chunk;
    int hi = lo + chunk; if (hi > end) hi = end;
    float m0 = -INFINITY, m1 = -INFINITY;
    int v = lo;
    for (; v + 3 < hi; v += 4) {
        unsigned u0 = *(const unsigned*)(h2 + (size_t)(v + 0) * D_H + f);
        unsigned u1 = *(const unsigned*)(h2 + (size_t)(v + 1) * D_H + f);
        unsigned u2 = *(const unsigned*)(h2 + (size_t)(v + 2) * D_H + f);
        unsigned u3 = *(const unsigned*)(h2 + (size_t)(v + 3) * D_H + f);
        m0 = fmaxf(m0, fmaxf(fmaxf(__uint_as_float(u0 << 16), __uint_as_float(u1 << 16)),
                             fmaxf(__uint_as_float(u2 << 16), __uint_as_float(u3 << 16))));
        m1 = fmaxf(m1, fmaxf(fmaxf(__uint_as_float(u0 & 0xFFFF0000u), __uint_as_float(u1 & 0xFFFF0000u)),
                             fmaxf(__uint_as_float(u2 & 0xFFFF0000u), __uint_as_float(u3 & 0xFFFF0000u))));
    }
    for (; v < hi; ++v) {
        unsigned u = *(const unsigned*)(h2 + (size_t)v * D_H + f);
        m0 = fmaxf(m0, __uint_as_float(u << 16));
        m1 = fmaxf(m1, __uint_as_float(u & 0xFFFF0000u));
    }
    float* p = pbuf + ((size_t)s * N_GRAPHS + g) * D_H + f;
    p[0] = m0;
    p[1] = m1;
}

__global__ void pool_max_final(const float* __restrict__ pbuf, float* __restrict__ gbuf) {
    int i = blockIdx.x * blockDim.x + threadIdx.x;
    if (i >= N_GRAPHS * D_H) return;
    float m = -INFINITY;
#pragma unroll
    for (int s = 0; s < PSPLIT; ++s) m = fmaxf(m, pbuf[(size_t)s * N_GRAPHS * D_H + i]);
    gbuf[i] = m;
}

extern "C" void kernel_launch(void* const* d_in, const int* in_sizes, int n_in,
                              void* d_out, int out_size, void* d_ws, size_t ws_size,
                              hipStream_t stream) {
    const float* x     = (const float*)d_in[0];
    const int*   ei    = (const int*)d_in[1];
    const int*   batch = (const int*)d_in[2];
    const float* Wg1   = (const float*)d_in[3];
    const float* bg1   = (const float*)d_in[4];
    const float* Wg2   = (const float*)d_in[5];
    const float* bg2   = (const float*)d_in[6];
    const float* W1    = (const float*)d_in[7];
    const float* b1    = (const float*)d_in[8];
    const float* W2    = (const float*)d_in[9];
    const float* b2    = (const float*)d_in[10];
    const float* gamma = (const float*)d_in[11];
    const float* beta  = (const float*)d_in[12];
    const int* src = ei;
    const int* dst = ei + N_EDGES;
    float* out = (float*)d_out;

    const int S1 = 8;  // fc1 K-split
    const int S2 = 8;  // fc2 K-split

    // workspace layout (16B-aligned)
    ushort_t* hpre   = (ushort_t*)d_ws;                        // [N_NODES, D_H] bf16
    ushort_t* h1b    = hpre + (size_t)N_NODES * D_H;           // [N_NODES, D_H] bf16
    ushort_t* w1t    = h1b + (size_t)N_NODES * D_H;            // [D_H, D_IN] bf16
    ushort_t* w2t    = w1t + (size_t)D_H * D_IN;               // [D_H, D_H] bf16
    ushort_t* xb     = w2t + (size_t)D_H * D_H;                // [N_NODES, D_IN] bf16
    float*    dinv   = (float*)(xb + (size_t)N_NODES * D_IN);  // [N_NODES]
    float*    gbuf   = dinv + N_NODES;                         // [N_GRAPHS, D_H]
    float*    pbuf   = gbuf + N_GRAPHS * D_H;                  // [PSPLIT, N_GRAPHS, D_H]
    float*    fc1o   = pbuf + (size_t)PSPLIT * N_GRAPHS * D_H; // [N_GRAPHS, D_FC]
    float*    part1  = fc1o + N_GRAPHS * D_FC;                 // [S1, 64, D_FC]
    float*    part2  = part1 + (size_t)S1 * N_GRAPHS * D_FC;   // [S2, 64, OUT_DIMS]
    int*      cursor = (int*)(part2 + (size_t)S2 * N_GRAPHS * OUT_DIMS);  // [N_NODES] -> degree
    int*      colbkt = cursor + N_NODES;                       // [N_NODES * BKT_CAP]
    int*      gstart = colbkt + (size_t)N_NODES * BKT_CAP;     // [N_GRAPHS+1]

    // ---- fused prep: zero cursor + W1^T + W2^T + x->bf16 + graph bounds ----
    prep_all<<<PREP_NBLK, 256, 0, stream>>>(Wg1, w1t, Wg2, w2t, x, xb, cursor, batch, gstart);

    // ---- bucket adjacency build ----
    fill_bucket<<<(N_EDGES + 255) / 256, 256, 0, stream>>>(src, dst, cursor, colbkt);
    compute_dinv<<<(N_NODES + 255) / 256, 256, 0, stream>>>(cursor, dinv);

    const int gconv = 2504;  // 313 row-tiles x 8 col-tiles, 1 wave each

    // conv1: hpre = bf16(xb @ Wg1) ; gather+relu -> h1b
    mfma_gemm_1w<<<gconv, 64, 0, stream>>>(xb, w1t, hpre, N_NODES, D_H, D_IN);
    gather_agg_relu_bf16<<<N_NODES / 4, 256, 0, stream>>>(hpre, cursor, colbkt, dinv, bg1, h1b);

    // conv2: hpre = bf16(h1b @ Wg2) ; gather+relu -> h2 (reuse h1b) ; pool
    mfma_gemm_1w<<<gconv, 64, 0, stream>>>(h1b, w2t, hpre, N_NODES, D_H, D_H);
    gather_agg_relu_bf16<<<N_NODES / 4, 256, 0, stream>>>(hpre, cursor, colbkt, dinv, bg2, h1b);
    pool_max_partial<<<dim3(N_GRAPHS, PSPLIT), 256, 0, stream>>>(h1b, gstart, pbuf);
    pool_max_final<<<(N_GRAPHS * D_H + 255) / 256, 256, 0, stream>>>(pbuf, gbuf);

    // fc1: [64,512]@[512,1024] split-K=8 -> part1 ; reduce + b1 + relu -> fc1o
    dim3 gfc1((D_FC + 63) / 64, 1, S1);
    gemm_splitk<<<gfc1, 256, 0, stream>>>(gbuf, W1, part1, N_GRAPHS, D_FC, D_H, D_H / S1);
    reduce_bias_relu<<<(N_GRAPHS * D_FC + 255) / 256, 256, 0, stream>>>(
        part1, b1, fc1o, N_GRAPHS * D_FC, D_FC, S1);

    // fc2: [64,1024]@[1024,5000] split-K=8 -> part2 ; reduce + BN + sigmoid -> out
    dim3 gfc2((OUT_DIMS + 63) / 64, 1, S2);
    gemm_splitk<<<gfc2, 256, 0, stream>>>(fc1o, W2, part2, N_GRAPHS, OUT_DIMS, D_FC, D_FC / S2);
    reduce_bn_sigmoid<<<(N_GRAPHS * OUT_DIMS + 255) / 256, 256, 0, stream>>>(
        part2, b2, gamma, beta, out, S2);
}